// Round 16
// baseline (135.232 us; speedup 1.0000x reference)
//
#include <hip/hip_runtime.h>
#include <stdint.h>

#define B_   16
#define CIN  4
#define COUT 8
#define H_   512
#define W_   512
#define HP   (H_ + 2)
#define WP   (W_ + 2)
#define PMAX 756
#define TBL  (2 * PMAX + 1)
#define RPB  8                    // output rows per block
#define GY   (H_ / RPB)           // 64
#define NBLK (2 * GY * B_)        // 2048 blocks
#define NQ   (B_ * HP)            // 8224 quant blocks (div by 8)

__device__ __forceinline__ int dot4(uint32_t a, int b, int c) {
#if __has_builtin(__builtin_amdgcn_sdot4)
    return __builtin_amdgcn_sdot4((int)a, b, c, false);
#else
    int r = c;
#pragma unroll
    for (int i = 0; i < 4; ++i) {
        int av = (int)((a >> (8 * i)) & 0xFFu);
        int bv = ((int)(((uint32_t)b) << (24 - 8 * i))) >> 24;
        r += av * bv;
    }
    return r;
#endif
}

__device__ __forceinline__ int dot8(uint32_t a, int b, int c) {
#if __has_builtin(__builtin_amdgcn_sdot8)
    return __builtin_amdgcn_sdot8((int)a, b, c, false);
#else
    int r = c;
#pragma unroll
    for (int i = 0; i < 8; ++i) {
        int av = (int)((a >> (4 * i)) & 0xFu);
        int bv = ((int)(((uint32_t)b) << (28 - 4 * i))) >> 28;
        r += av * bv;
    }
    return r;
#endif
}

__device__ __forceinline__ float rfl_f(float v) {
    return __int_as_float(__builtin_amdgcn_readfirstlane(__float_as_int(v)));
}
__device__ __forceinline__ float recip1(float d) {
    float y0 = __builtin_amdgcn_rcpf(d);
    float e  = fmaf(-d, y0, 1.0f);
    return fmaf(y0, e, y0);
}
// Markstein correctly-rounded division (bit-exact vs __fdiv_rn; validated r12/r13)
__device__ __forceinline__ float mdiv(float n, float d, float y) {
    float q0 = __fmul_rn(n, y);
    float rr = fmaf(-d, q0, n);
    return fmaf(rr, y, q0);
}

__device__ __forceinline__ int wquant(const float* w, float s_w,
                                      int co, int ci, int tap) {
    const int kh = tap / 3, kw = tap % 3;
    float wv = w[((co * CIN + ci) * 3 + kh) * 3 + kw];
    float q  = rintf(__fdiv_rn(wv, s_w));
    q = fminf(fmaxf(q, -7.0f), 7.0f);
    return (int)q;
}

// ---------------- quant + weight pack ----------------
__global__ __launch_bounds__(128) void quant_pack_kernel(
        const float* __restrict__ x, const float* __restrict__ weight,
        const float* __restrict__ s_in_p, const float* __restrict__ s_w_p,
        uint32_t* __restrict__ xq, uint32_t* __restrict__ wq8) {
    const int raw = blockIdx.x;
    const int lin = (raw & 7) * (NQ / 8) + (raw >> 3);
    const int b = lin / HP, hp = lin % HP;
    const int t = threadIdx.x;
    if (raw == 0) {
        const float s_w = *s_w_p;
        if (t < 32) {                        // nibble pairs (0,1)(3,4)(6,7)(2,5)
            const int co = t >> 2, p = t & 3;
            const int tA = (p == 0) ? 0 : (p == 1) ? 3 : (p == 2) ? 6 : 2;
            const int tB = (p == 0) ? 1 : (p == 1) ? 4 : (p == 2) ? 7 : 5;
            uint32_t v = 0;
#pragma unroll
            for (int ci = 0; ci < CIN; ++ci) {
                v |= ((uint32_t)(wquant(weight, s_w, co, ci, tA) & 0xF)) << (8 * ci);
                v |= ((uint32_t)(wquant(weight, s_w, co, ci, tB) & 0xF)) << (8 * ci + 4);
            }
            wq8[t] = v;
        } else if (t < 40) {                 // tap-8 bytes
            const int co = t - 32;
            uint32_t v = 0;
#pragma unroll
            for (int ci = 0; ci < CIN; ++ci)
                v |= ((uint32_t)(wquant(weight, s_w, co, ci, 8) & 0xFF)) << (8 * ci);
            wq8[32 + co] = v;
        }
    }
    uint32_t* dst = xq + ((size_t)b * HP + hp) * WP;
    if (hp == 0 || hp == HP - 1) {
        for (int i = t; i < WP; i += 128) dst[i] = 0;
        return;
    }
    const float s_in = *s_in_p;
    const float yin  = recip1(s_in);
    const int h = hp - 1;
    const size_t plane = (size_t)H_ * W_;
    const float* xr = x + ((size_t)b * CIN) * plane + (size_t)h * W_ + 4 * t;
    float4 v0 = *(const float4*)(xr);
    float4 v1 = *(const float4*)(xr + plane);
    float4 v2 = *(const float4*)(xr + 2 * plane);
    float4 v3 = *(const float4*)(xr + 3 * plane);
    uint32_t o0 = 0, o1 = 0, o2 = 0, o3 = 0;
#define QP(f, ci, oj)                                                  \
    { float q = rintf(mdiv((f), s_in, yin));                           \
      q = fminf(fmaxf(q, 0.0f), 255.0f);                               \
      oj |= ((uint32_t)(int)q) << (8 * (ci)); }
    QP(v0.x, 0, o0) QP(v0.y, 0, o1) QP(v0.z, 0, o2) QP(v0.w, 0, o3)
    QP(v1.x, 1, o0) QP(v1.y, 1, o1) QP(v1.z, 1, o2) QP(v1.w, 1, o3)
    QP(v2.x, 2, o0) QP(v2.y, 2, o1) QP(v2.z, 2, o2) QP(v2.w, 2, o3)
    QP(v3.x, 3, o0) QP(v3.y, 3, o1) QP(v3.z, 3, o2) QP(v3.w, 3, o3)
#undef QP
    uint32_t* d = dst + 1 + 4 * t;
    uint4 vv;
    vv.x = o0; vv.y = o1; vv.z = o2; vv.w = o3;
    *(uint4*)d = vv;                      // guaranteed dwordx4 store
    if (t == 0) dst[0] = 0;
    if (t == 127) dst[WP - 1] = 0;
}

// ---------------- shared conv machinery ----------------
#define LOADW()                                                              \
    int w8s[32], w4s[8];                                                     \
    {                                                                        \
        const int4* q4 = (const int4*)wq8;                                   \
        _Pragma("unroll")                                                    \
        for (int i = 0; i < 8; ++i) {                                        \
            int4 w4i = q4[i];                                                \
            w8s[4 * i + 0] = w4i.x;                                          \
            w8s[4 * i + 1] = w4i.y;                                          \
            w8s[4 * i + 2] = w4i.z;                                          \
            w8s[4 * i + 3] = w4i.w;                                          \
        }                                                                    \
        int4 a0 = q4[8], a1 = q4[9];                                         \
        w4s[0] = a0.x; w4s[1] = a0.y; w4s[2] = a0.z; w4s[3] = a0.w;          \
        w4s[4] = a1.x; w4s[5] = a1.y; w4s[6] = a1.z; w4s[7] = a1.w;          \
    }

#define SWZ()                                                                \
    const int raw = blockIdx.x;                                              \
    const int lin = (raw & 7) * (NBLK / 8) + (raw >> 3);                     \
    const int bx = lin & 1;                                                  \
    const int hy = (lin >> 1) & (GY - 1);                                    \
    const int b  = lin >> 7;                                                 \
    const int w0 = bx * 256 + threadIdx.x;                                   \
    const int h0 = hy * RPB;

#define EXTS(CA, SG, v0, v1, v2)                                             \
    do {                                                                     \
        uint32_t lo_ = ((v0) & 0x0F0F0F0Fu) | (((v1) << 4) & 0xF0F0F0F0u);   \
        uint32_t hi_ = (((v0) >> 4) & 0x0F0F0F0Fu) | ((v1) & 0xF0F0F0F0u);   \
        CA[0] = lo_ & 0x33333333u;                                           \
        CA[1] = (lo_ >> 2) & 0x33333333u;                                    \
        CA[2] = hi_ & 0x33333333u;                                           \
        CA[3] = (hi_ >> 2) & 0x33333333u;                                    \
        SG[0] = (v2)&0x03030303u;                                            \
        SG[1] = ((v2) >> 2) & 0x03030303u;                                   \
        SG[2] = ((v2) >> 4) & 0x03030303u;                                   \
        SG[3] = ((v2) >> 6) & 0x03030303u;                                   \
    } while (0)

#define RING_INIT()                                                          \
    uint32_t cA0[4], cA1[4], cA2[4], cA3[4];                                 \
    uint32_t sg0[4], sg1[4], sg2[4], sg3[4];                                 \
    {                                                                        \
        uint32_t r0 = base[0], r1 = base[1], r2 = base[2];                   \
        EXTS(cA0, sg0, r0, r1, r2);                                          \
        r0 = base[WP]; r1 = base[WP + 1]; r2 = base[WP + 2];                 \
        EXTS(cA1, sg1, r0, r1, r2);                                          \
    }                                                                        \
    uint32_t n0 = base[2 * WP], n1 = base[2 * WP + 1], n2 = base[2 * WP + 2];

#define PREF(S)                                                              \
    if ((S) < RPB - 1) {                                                     \
        const uint32_t* nr_ = base + (size_t)((S) + 3) * WP;                 \
        n0 = nr_[0]; n1 = nr_[1]; n2 = nr_[2];                               \
    }

#define DOTS(CAa, SGa, CAb, SGb, CAc, SGc, K, INIT, OUTV)                    \
    {                                                                        \
        int a_ = dot4(SGc[K], w4s[co], INIT);                                \
        a_ = dot8(CAa[K], w8s[co * 4 + 0], a_);                              \
        a_ = dot8(CAb[K], w8s[co * 4 + 1], a_);                              \
        a_ = dot8(CAc[K], w8s[co * 4 + 2], a_);                              \
        a_ = dot8(K == 0 ? pc0 : K == 1 ? pc1 : K == 2 ? pc2 : pc3,          \
                  w8s[co * 4 + 3], a_);                                      \
        OUTV = a_;                                                           \
    }

// ---------------- pass 1: absmax ----------------
#define STEP1(S, CAa, SGa, CAb, SGb, CAc, SGc)                               \
    do {                                                                     \
        EXTS(CAc, SGc, n0, n1, n2);                                          \
        PREF(S);                                                             \
        const uint32_t pc0 = SGa[0] | (SGb[0] << 4);                         \
        const uint32_t pc1 = SGa[1] | (SGb[1] << 4);                         \
        const uint32_t pc2 = SGa[2] | (SGb[2] << 4);                         \
        const uint32_t pc3 = SGa[3] | (SGb[3] << 4);                         \
        _Pragma("unroll")                                                    \
        for (int co = 0; co < COUT; ++co) {                                  \
            int a0, a1, a2, a3;                                              \
            DOTS(CAa, SGa, CAb, SGb, CAc, SGc, 0, 0, a0);                    \
            DOTS(CAa, SGa, CAb, SGb, CAc, SGc, 1, 0, a1);                    \
            DOTS(CAa, SGa, CAb, SGb, CAc, SGc, 2, 0, a2);                    \
            DOTS(CAa, SGa, CAb, SGb, CAc, SGc, 3, 0, a3);                    \
            rMax0 = max(rMax0, a0); rMin0 = min(rMin0, a0);                  \
            rMax1 = max(rMax1, a1); rMin1 = min(rMin1, a1);                  \
            rMax2 = max(rMax2, a2); rMin2 = min(rMin2, a2);                  \
            rMax3 = max(rMax3, a3); rMin3 = min(rMin3, a3);                  \
        }                                                                    \
    } while (0)

__global__ __launch_bounds__(256, 2) void conv_absmax(
        const uint32_t* __restrict__ xq, const uint32_t* __restrict__ wq8,
        int* __restrict__ blkmax) {
    __shared__ int red[4];
    LOADW();
    SWZ();
    const uint32_t* base = xq + ((size_t)b * HP + h0) * WP + w0;
    RING_INIT();
    int rMax0 = 0, rMax1 = 0, rMax2 = 0, rMax3 = 0;
    int rMin0 = 0, rMin1 = 0, rMin2 = 0, rMin3 = 0;
    STEP1(0, cA0, sg0, cA1, sg1, cA2, sg2);
    STEP1(1, cA1, sg1, cA2, sg2, cA3, sg3);
    STEP1(2, cA2, sg2, cA3, sg3, cA0, sg0);
    STEP1(3, cA3, sg3, cA0, sg0, cA1, sg1);
    STEP1(4, cA0, sg0, cA1, sg1, cA2, sg2);
    STEP1(5, cA1, sg1, cA2, sg2, cA3, sg3);
    STEP1(6, cA2, sg2, cA3, sg3, cA0, sg0);
    STEP1(7, cA3, sg3, cA0, sg0, cA1, sg1);
    int m = max(max(max(rMax0, -rMin0), max(rMax1, -rMin1)),
                max(max(rMax2, -rMin2), max(rMax3, -rMin3)));
#pragma unroll
    for (int off = 1; off < 64; off <<= 1)
        m = max(m, __shfl_xor(m, off));
    if ((threadIdx.x & 63) == 0) red[threadIdx.x >> 6] = m;
    __syncthreads();
    if (threadIdx.x == 0)
        blkmax[raw] = max(max(red[0], red[1]), max(red[2], red[3]));
}

__global__ __launch_bounds__(256) void reduce_absmax(
        const int* __restrict__ blkmax, int* __restrict__ absmax) {
    __shared__ int red[4];
    const int t = threadIdx.x;
    int m = 0;
#pragma unroll
    for (int i = 0; i < NBLK / 256; ++i) m = max(m, blkmax[t + 256 * i]);
#pragma unroll
    for (int off = 1; off < 64; off <<= 1)
        m = max(m, __shfl_xor(m, off));
    if ((t & 63) == 0) red[t >> 6] = m;
    __syncthreads();
    if (t == 0)
        *absmax = max(max(red[0], red[1]), max(red[2], red[3]));
}

// ---------------- pass 2: LUT + dieted epilogue (r12 form) ----------------
#define STEP2(S, CAa, SGa, CAb, SGb, CAc, SGc)                               \
    do {                                                                     \
        EXTS(CAc, SGc, n0, n1, n2);                                          \
        PREF(S);                                                             \
        const uint32_t pc0 = SGa[0] | (SGb[0] << 4);                         \
        const uint32_t pc1 = SGa[1] | (SGb[1] << 4);                         \
        const uint32_t pc2 = SGa[2] | (SGb[2] << 4);                         \
        const uint32_t pc3 = SGa[3] | (SGb[3] << 4);                         \
        int ax[COUT][4];                                                     \
        _Pragma("unroll")                                                    \
        for (int co = 0; co < COUT; ++co) {                                  \
            DOTS(CAa, SGa, CAb, SGb, CAc, SGc, 0, PMAX, ax[co][0]);          \
            DOTS(CAa, SGa, CAb, SGb, CAc, SGc, 1, PMAX, ax[co][1]);          \
            DOTS(CAa, SGa, CAb, SGb, CAc, SGc, 2, PMAX, ax[co][2]);          \
            DOTS(CAa, SGa, CAb, SGb, CAc, SGc, 3, PMAX, ax[co][3]);          \
        }                                                                    \
        float tv[COUT][4];                                                   \
        _Pragma("unroll")                                                    \
        for (int co = 0; co < COUT; ++co) {                                  \
            tv[co][0] = T0[ax[co][0]];                                       \
            tv[co][1] = T4[ax[co][1]];                                       \
            tv[co][2] = T0[ax[co][2]];                                       \
            tv[co][3] = T4[ax[co][3]];                                       \
        }                                                                    \
        float* orow = out + ((size_t)b * COUT * H_ + (size_t)(h0 + (S))) * W_ + w0; \
        _Pragma("unroll")                                                    \
        for (int co = 0; co < COUT; ++co) {                                  \
            float of = __fadd_rn(tv[co][0], tv[co][1]);                      \
            of = __fadd_rn(of, __fmul_rn(tv[co][2], 16.0f));                 \
            of = __fadd_rn(of, __fmul_rn(tv[co][3], 16.0f));                 \
            float o_ = __fadd_rn(__fmul_rn(of, scale), br[co]);              \
            float q0 = __fmul_rn(o_, y1);                                    \
            float rr = fmaf(-s_out, q0, o_);                                 \
            float qd = fmaf(rr, y1, q0);                                     \
            float q_ = rintf(qd);                                            \
            q_ = fminf(fmaxf(q_, -127.0f), 127.0f);                          \
            orow[(size_t)co * plane] = __fmul_rn(q_, s_out);                 \
        }                                                                    \
    } while (0)

__global__ __launch_bounds__(256, 2) void conv_out(
        const uint32_t* __restrict__ xq, const uint32_t* __restrict__ wq8,
        const float* __restrict__ bias, const float* __restrict__ sp_in,
        const float* __restrict__ sp_w, const float* __restrict__ sp_out,
        const int* __restrict__ absmax, float* __restrict__ out) {
    __shared__ float T0[TBL];
    __shared__ float T4[TBL];
    LOADW();
    const float pabs = fmaxf((float)(*absmax), 1e-6f);
    const float c63  = 1.0f / 63.0f;
    float g = rintf(__fdiv_rn(127.0f, __fmul_rn(pabs, c63)));
    g = fminf(fmaxf(g, 1.0f), 255.0f);
    const float step = __fdiv_rn(1.0f, __fmul_rn(g, c63));
    for (int i = threadIdx.x; i < TBL; i += 256) {
        float p = (float)(i - PMAX);
        float r = rintf(__fdiv_rn(p, step));
        r = fminf(fmaxf(r, -127.0f), 127.0f);
        float v = __fmul_rn(r, step);
        T0[i] = v;
        T4[i] = 4.0f * v;          // exact
    }
    const float scale = __fmul_rn(rfl_f(*sp_in), rfl_f(*sp_w));
    const float s_out = rfl_f(*sp_out);
    const float y1    = recip1(s_out);
    float br[COUT];
#pragma unroll
    for (int co = 0; co < COUT; ++co) br[co] = rfl_f(bias[co]);
    __syncthreads();

    SWZ();
    const uint32_t* base = xq + ((size_t)b * HP + h0) * WP + w0;
    const size_t plane = (size_t)H_ * W_;
    RING_INIT();
    STEP2(0, cA0, sg0, cA1, sg1, cA2, sg2);
    STEP2(1, cA1, sg1, cA2, sg2, cA3, sg3);
    STEP2(2, cA2, sg2, cA3, sg3, cA0, sg0);
    STEP2(3, cA3, sg3, cA0, sg0, cA1, sg1);
    STEP2(4, cA0, sg0, cA1, sg1, cA2, sg2);
    STEP2(5, cA1, sg1, cA2, sg2, cA3, sg3);
    STEP2(6, cA2, sg2, cA3, sg3, cA0, sg0);
    STEP2(7, cA3, sg3, cA0, sg0, cA1, sg1);
}

extern "C" void kernel_launch(void* const* d_in, const int* in_sizes, int n_in,
                              void* d_out, int out_size, void* d_ws, size_t ws_size,
                              hipStream_t stream) {
    const float* x      = (const float*)d_in[0];
    const float* weight = (const float*)d_in[1];
    const float* bias   = (const float*)d_in[2];
    const float* s_in   = (const float*)d_in[3];
    const float* s_w    = (const float*)d_in[4];
    const float* s_out  = (const float*)d_in[5];
    float* out = (float*)d_out;

    int*      absmax = (int*)d_ws;
    uint32_t* wq8    = (uint32_t*)((char*)d_ws + 256);    // 40 u32
    int*      blkmax = (int*)((char*)d_ws + 1024);        // 2048 ints
    uint32_t* xq     = (uint32_t*)((char*)d_ws + 16384);

    quant_pack_kernel<<<dim3(NQ), dim3(128), 0, stream>>>(
        x, weight, s_in, s_w, xq, wq8);

    conv_absmax<<<dim3(NBLK), dim3(256), 0, stream>>>(xq, wq8, blkmax);

    reduce_absmax<<<dim3(1), dim3(256), 0, stream>>>(blkmax, absmax);

    // DIAGNOSTIC: conv_out launched TWICE (idempotent — identical inputs ->
    // identical stores). Bench delta vs r15 (92.8) = conv_out's TRUE cost,
    // untangling the rocprof replay inflation seen since round 1.
    conv_out<<<dim3(NBLK), dim3(256), 0, stream>>>(
        xq, wq8, bias, s_in, s_w, s_out, absmax, out);
    conv_out<<<dim3(NBLK), dim3(256), 0, stream>>>(
        xq, wq8, bias, s_in, s_w, s_out, absmax, out);
}

// Round 17
// 98.466 us; speedup vs baseline: 1.3734x; 1.3734x over previous
//
#include <hip/hip_runtime.h>
#include <stdint.h>

#define B_   16
#define CIN  4
#define COUT 8
#define H_   512
#define W_   512
#define HP   (H_ + 2)
#define WP   (W_ + 2)
#define PMAX 756
#define TBL  (2 * PMAX + 1)
#define RPB  8                    // output rows per block
#define GY   (H_ / RPB)           // 64
#define NBLK (2 * GY * B_)        // 2048 blocks
#define NQ   (B_ * HP)            // 8224 quant blocks (div by 8)

__device__ __forceinline__ int dot4(uint32_t a, int b, int c) {
#if __has_builtin(__builtin_amdgcn_sdot4)
    return __builtin_amdgcn_sdot4((int)a, b, c, false);
#else
    int r = c;
#pragma unroll
    for (int i = 0; i < 4; ++i) {
        int av = (int)((a >> (8 * i)) & 0xFFu);
        int bv = ((int)(((uint32_t)b) << (24 - 8 * i))) >> 24;
        r += av * bv;
    }
    return r;
#endif
}

__device__ __forceinline__ int dot8(uint32_t a, int b, int c) {
#if __has_builtin(__builtin_amdgcn_sdot8)
    return __builtin_amdgcn_sdot8((int)a, b, c, false);
#else
    int r = c;
#pragma unroll
    for (int i = 0; i < 8; ++i) {
        int av = (int)((a >> (4 * i)) & 0xFu);
        int bv = ((int)(((uint32_t)b) << (28 - 4 * i))) >> 28;
        r += av * bv;
    }
    return r;
#endif
}

__device__ __forceinline__ float rfl_f(float v) {
    return __int_as_float(__builtin_amdgcn_readfirstlane(__float_as_int(v)));
}
__device__ __forceinline__ float recip1(float d) {
    float y0 = __builtin_amdgcn_rcpf(d);
    float e  = fmaf(-d, y0, 1.0f);
    return fmaf(y0, e, y0);
}
// Markstein correctly-rounded division (bit-exact vs __fdiv_rn; validated r12/r13)
__device__ __forceinline__ float mdiv(float n, float d, float y) {
    float q0 = __fmul_rn(n, y);
    float rr = fmaf(-d, q0, n);
    return fmaf(rr, y, q0);
}

__device__ __forceinline__ int wquant(const float* w, float s_w,
                                      int co, int ci, int tap) {
    const int kh = tap / 3, kw = tap % 3;
    float wv = w[((co * CIN + ci) * 3 + kh) * 3 + kw];
    float q  = rintf(__fdiv_rn(wv, s_w));
    q = fminf(fmaxf(q, -7.0f), 7.0f);
    return (int)q;
}

// ---------------- quant + weight pack (unchanged) ----------------
__global__ __launch_bounds__(128) void quant_pack_kernel(
        const float* __restrict__ x, const float* __restrict__ weight,
        const float* __restrict__ s_in_p, const float* __restrict__ s_w_p,
        uint32_t* __restrict__ xq, uint32_t* __restrict__ wq8) {
    const int raw = blockIdx.x;
    const int lin = (raw & 7) * (NQ / 8) + (raw >> 3);
    const int b = lin / HP, hp = lin % HP;
    const int t = threadIdx.x;
    if (raw == 0) {
        const float s_w = *s_w_p;
        if (t < 32) {                        // nibble pairs (0,1)(3,4)(6,7)(2,5)
            const int co = t >> 2, p = t & 3;
            const int tA = (p == 0) ? 0 : (p == 1) ? 3 : (p == 2) ? 6 : 2;
            const int tB = (p == 0) ? 1 : (p == 1) ? 4 : (p == 2) ? 7 : 5;
            uint32_t v = 0;
#pragma unroll
            for (int ci = 0; ci < CIN; ++ci) {
                v |= ((uint32_t)(wquant(weight, s_w, co, ci, tA) & 0xF)) << (8 * ci);
                v |= ((uint32_t)(wquant(weight, s_w, co, ci, tB) & 0xF)) << (8 * ci + 4);
            }
            wq8[t] = v;
        } else if (t < 40) {                 // tap-8 bytes
            const int co = t - 32;
            uint32_t v = 0;
#pragma unroll
            for (int ci = 0; ci < CIN; ++ci)
                v |= ((uint32_t)(wquant(weight, s_w, co, ci, 8) & 0xFF)) << (8 * ci);
            wq8[32 + co] = v;
        }
    }
    uint32_t* dst = xq + ((size_t)b * HP + hp) * WP;
    if (hp == 0 || hp == HP - 1) {
        for (int i = t; i < WP; i += 128) dst[i] = 0;
        return;
    }
    const float s_in = *s_in_p;
    const float yin  = recip1(s_in);
    const int h = hp - 1;
    const size_t plane = (size_t)H_ * W_;
    const float* xr = x + ((size_t)b * CIN) * plane + (size_t)h * W_ + 4 * t;
    float4 v0 = *(const float4*)(xr);
    float4 v1 = *(const float4*)(xr + plane);
    float4 v2 = *(const float4*)(xr + 2 * plane);
    float4 v3 = *(const float4*)(xr + 3 * plane);
    uint32_t o0 = 0, o1 = 0, o2 = 0, o3 = 0;
#define QP(f, ci, oj)                                                  \
    { float q = rintf(mdiv((f), s_in, yin));                           \
      q = fminf(fmaxf(q, 0.0f), 255.0f);                               \
      oj |= ((uint32_t)(int)q) << (8 * (ci)); }
    QP(v0.x, 0, o0) QP(v0.y, 0, o1) QP(v0.z, 0, o2) QP(v0.w, 0, o3)
    QP(v1.x, 1, o0) QP(v1.y, 1, o1) QP(v1.z, 1, o2) QP(v1.w, 1, o3)
    QP(v2.x, 2, o0) QP(v2.y, 2, o1) QP(v2.z, 2, o2) QP(v2.w, 2, o3)
    QP(v3.x, 3, o0) QP(v3.y, 3, o1) QP(v3.z, 3, o2) QP(v3.w, 3, o3)
#undef QP
    uint32_t* d = dst + 1 + 4 * t;
    uint4 vv;
    vv.x = o0; vv.y = o1; vv.z = o2; vv.w = o3;
    *(uint4*)d = vv;
    if (t == 0) dst[0] = 0;
    if (t == 127) dst[WP - 1] = 0;
}

// ---------------- shared conv machinery ----------------
#define LOADW()                                                              \
    int w8s[32], w4s[8];                                                     \
    {                                                                        \
        const int4* q4 = (const int4*)wq8;                                   \
        _Pragma("unroll")                                                    \
        for (int i = 0; i < 8; ++i) {                                        \
            int4 w4i = q4[i];                                                \
            w8s[4 * i + 0] = w4i.x;                                          \
            w8s[4 * i + 1] = w4i.y;                                          \
            w8s[4 * i + 2] = w4i.z;                                          \
            w8s[4 * i + 3] = w4i.w;                                          \
        }                                                                    \
        int4 a0 = q4[8], a1 = q4[9];                                         \
        w4s[0] = a0.x; w4s[1] = a0.y; w4s[2] = a0.z; w4s[3] = a0.w;          \
        w4s[4] = a1.x; w4s[5] = a1.y; w4s[6] = a1.z; w4s[7] = a1.w;          \
    }

#define SWZ()                                                                \
    const int raw = blockIdx.x;                                              \
    const int lin = (raw & 7) * (NBLK / 8) + (raw >> 3);                     \
    const int bx = lin & 1;                                                  \
    const int hy = (lin >> 1) & (GY - 1);                                    \
    const int b  = lin >> 7;                                                 \
    const int w0 = bx * 256 + threadIdx.x;                                   \
    const int h0 = hy * RPB;

#define EXTS(CA, SG, v0, v1, v2)                                             \
    do {                                                                     \
        uint32_t lo_ = ((v0) & 0x0F0F0F0Fu) | (((v1) << 4) & 0xF0F0F0F0u);   \
        uint32_t hi_ = (((v0) >> 4) & 0x0F0F0F0Fu) | ((v1) & 0xF0F0F0F0u);   \
        CA[0] = lo_ & 0x33333333u;                                           \
        CA[1] = (lo_ >> 2) & 0x33333333u;                                    \
        CA[2] = hi_ & 0x33333333u;                                           \
        CA[3] = (hi_ >> 2) & 0x33333333u;                                    \
        SG[0] = (v2)&0x03030303u;                                            \
        SG[1] = ((v2) >> 2) & 0x03030303u;                                   \
        SG[2] = ((v2) >> 4) & 0x03030303u;                                   \
        SG[3] = ((v2) >> 6) & 0x03030303u;                                   \
    } while (0)

// I$-diet: ROLLED row loop (#pragma unroll 1). 3-slot named window + explicit
// rotation keeps all indices compile-time (no scratch) while shrinking the
// body ~8x so 8 waves/SIMD stop thrashing the shared 32KB I$.
#define ROTATE()                                                             \
    _Pragma("unroll")                                                        \
    for (int k = 0; k < 4; ++k) {                                            \
        cAa[k] = cAb[k]; sga[k] = sgb[k];                                    \
        cAb[k] = cAc[k]; sgb[k] = sgc[k];                                    \
    }

#define DOTS3(K, INIT, OUTV)                                                 \
    {                                                                        \
        int a_ = dot4(sgc[K], w4s[co], INIT);                                \
        a_ = dot8(cAa[K], w8s[co * 4 + 0], a_);                              \
        a_ = dot8(cAb[K], w8s[co * 4 + 1], a_);                              \
        a_ = dot8(cAc[K], w8s[co * 4 + 2], a_);                              \
        a_ = dot8(K == 0 ? pc0 : K == 1 ? pc1 : K == 2 ? pc2 : pc3,          \
                  w8s[co * 4 + 3], a_);                                      \
        OUTV = a_;                                                           \
    }

#define WIN_INIT()                                                           \
    uint32_t cAa[4], cAb[4], cAc[4];                                         \
    uint32_t sga[4], sgb[4], sgc[4];                                         \
    {                                                                        \
        uint32_t r0 = base[0], r1 = base[1], r2 = base[2];                   \
        EXTS(cAa, sga, r0, r1, r2);                                          \
        r0 = base[WP]; r1 = base[WP + 1]; r2 = base[WP + 2];                 \
        EXTS(cAb, sgb, r0, r1, r2);                                          \
    }                                                                        \
    uint32_t n0 = base[2 * WP], n1 = base[2 * WP + 1], n2 = base[2 * WP + 2];\
    const uint32_t* nextr = base + 3 * WP;

// ---------------- pass 1: absmax ----------------
__global__ __launch_bounds__(256, 2) void conv_absmax(
        const uint32_t* __restrict__ xq, const uint32_t* __restrict__ wq8,
        int* __restrict__ blkmax) {
    __shared__ int red[4];
    LOADW();
    SWZ();
    const uint32_t* base = xq + ((size_t)b * HP + h0) * WP + w0;
    WIN_INIT();
    int rMax0 = 0, rMax1 = 0, rMax2 = 0, rMax3 = 0;
    int rMin0 = 0, rMin1 = 0, rMin2 = 0, rMin3 = 0;
#pragma unroll 1
    for (int s = 0; s < RPB; ++s) {
        EXTS(cAc, sgc, n0, n1, n2);
        if (s < RPB - 1) {
            n0 = nextr[0]; n1 = nextr[1]; n2 = nextr[2];
            nextr += WP;
        }
        const uint32_t pc0 = sga[0] | (sgb[0] << 4);
        const uint32_t pc1 = sga[1] | (sgb[1] << 4);
        const uint32_t pc2 = sga[2] | (sgb[2] << 4);
        const uint32_t pc3 = sga[3] | (sgb[3] << 4);
#pragma unroll
        for (int co = 0; co < COUT; ++co) {
            int a0, a1, a2, a3;
            DOTS3(0, 0, a0);
            DOTS3(1, 0, a1);
            DOTS3(2, 0, a2);
            DOTS3(3, 0, a3);
            rMax0 = max(rMax0, a0); rMin0 = min(rMin0, a0);
            rMax1 = max(rMax1, a1); rMin1 = min(rMin1, a1);
            rMax2 = max(rMax2, a2); rMin2 = min(rMin2, a2);
            rMax3 = max(rMax3, a3); rMin3 = min(rMin3, a3);
        }
        ROTATE();
    }
    int m = max(max(max(rMax0, -rMin0), max(rMax1, -rMin1)),
                max(max(rMax2, -rMin2), max(rMax3, -rMin3)));
#pragma unroll
    for (int off = 1; off < 64; off <<= 1)
        m = max(m, __shfl_xor(m, off));
    if ((threadIdx.x & 63) == 0) red[threadIdx.x >> 6] = m;
    __syncthreads();
    if (threadIdx.x == 0)
        blkmax[raw] = max(max(red[0], red[1]), max(red[2], red[3]));
}

__global__ __launch_bounds__(256) void reduce_absmax(
        const int* __restrict__ blkmax, int* __restrict__ absmax) {
    __shared__ int red[4];
    const int t = threadIdx.x;
    int m = 0;
#pragma unroll
    for (int i = 0; i < NBLK / 256; ++i) m = max(m, blkmax[t + 256 * i]);
#pragma unroll
    for (int off = 1; off < 64; off <<= 1)
        m = max(m, __shfl_xor(m, off));
    if ((t & 63) == 0) red[t >> 6] = m;
    __syncthreads();
    if (t == 0)
        *absmax = max(max(red[0], red[1]), max(red[2], red[3]));
}

// ---------------- pass 2: LUT + dieted epilogue, rolled loop ----------------
__global__ __launch_bounds__(256, 2) void conv_out(
        const uint32_t* __restrict__ xq, const uint32_t* __restrict__ wq8,
        const float* __restrict__ bias, const float* __restrict__ sp_in,
        const float* __restrict__ sp_w, const float* __restrict__ sp_out,
        const int* __restrict__ absmax, float* __restrict__ out) {
    __shared__ float T0[TBL];
    __shared__ float T4[TBL];
    LOADW();
    const float pabs = fmaxf((float)(*absmax), 1e-6f);
    const float c63  = 1.0f / 63.0f;
    float g = rintf(__fdiv_rn(127.0f, __fmul_rn(pabs, c63)));
    g = fminf(fmaxf(g, 1.0f), 255.0f);
    const float step = __fdiv_rn(1.0f, __fmul_rn(g, c63));
    for (int i = threadIdx.x; i < TBL; i += 256) {
        float p = (float)(i - PMAX);
        float r = rintf(__fdiv_rn(p, step));
        r = fminf(fmaxf(r, -127.0f), 127.0f);
        float v = __fmul_rn(r, step);
        T0[i] = v;
        T4[i] = 4.0f * v;          // exact
    }
    const float scale = __fmul_rn(rfl_f(*sp_in), rfl_f(*sp_w));
    const float s_out = rfl_f(*sp_out);
    const float y1    = recip1(s_out);
    float br[COUT];
#pragma unroll
    for (int co = 0; co < COUT; ++co) br[co] = rfl_f(bias[co]);
    __syncthreads();

    SWZ();
    const uint32_t* base = xq + ((size_t)b * HP + h0) * WP + w0;
    const size_t plane = (size_t)H_ * W_;
    WIN_INIT();
    float* orow = out + ((size_t)b * COUT * H_ + (size_t)h0) * W_ + w0;
#pragma unroll 1
    for (int s = 0; s < RPB; ++s) {
        EXTS(cAc, sgc, n0, n1, n2);
        if (s < RPB - 1) {
            n0 = nextr[0]; n1 = nextr[1]; n2 = nextr[2];
            nextr += WP;
        }
        const uint32_t pc0 = sga[0] | (sgb[0] << 4);
        const uint32_t pc1 = sga[1] | (sgb[1] << 4);
        const uint32_t pc2 = sga[2] | (sgb[2] << 4);
        const uint32_t pc3 = sga[3] | (sgb[3] << 4);
#pragma unroll
        for (int co = 0; co < COUT; ++co) {
            int a0, a1, a2, a3;
            DOTS3(0, PMAX, a0);
            DOTS3(1, PMAX, a1);
            DOTS3(2, PMAX, a2);
            DOTS3(3, PMAX, a3);
            float of = __fadd_rn(T0[a0], T4[a1]);
            of = __fadd_rn(of, __fmul_rn(T0[a2], 16.0f));
            of = __fadd_rn(of, __fmul_rn(T4[a3], 16.0f));
            float o_ = __fadd_rn(__fmul_rn(of, scale), br[co]);
            float q0 = __fmul_rn(o_, y1);
            float rr = fmaf(-s_out, q0, o_);
            float qd = fmaf(rr, y1, q0);
            float q_ = rintf(qd);
            q_ = fminf(fmaxf(q_, -127.0f), 127.0f);
            orow[(size_t)co * plane] = __fmul_rn(q_, s_out);
        }
        ROTATE();
        orow += W_;
    }
}

extern "C" void kernel_launch(void* const* d_in, const int* in_sizes, int n_in,
                              void* d_out, int out_size, void* d_ws, size_t ws_size,
                              hipStream_t stream) {
    const float* x      = (const float*)d_in[0];
    const float* weight = (const float*)d_in[1];
    const float* bias   = (const float*)d_in[2];
    const float* s_in   = (const float*)d_in[3];
    const float* s_w    = (const float*)d_in[4];
    const float* s_out  = (const float*)d_in[5];
    float* out = (float*)d_out;

    int*      absmax = (int*)d_ws;
    uint32_t* wq8    = (uint32_t*)((char*)d_ws + 256);    // 40 u32
    int*      blkmax = (int*)((char*)d_ws + 1024);        // 2048 ints
    uint32_t* xq     = (uint32_t*)((char*)d_ws + 16384);

    quant_pack_kernel<<<dim3(NQ), dim3(128), 0, stream>>>(
        x, weight, s_in, s_w, xq, wq8);

    conv_absmax<<<dim3(NBLK), dim3(256), 0, stream>>>(xq, wq8, blkmax);

    reduce_absmax<<<dim3(1), dim3(256), 0, stream>>>(blkmax, absmax);

    conv_out<<<dim3(NBLK), dim3(256), 0, stream>>>(
        xq, wq8, bias, s_in, s_w, s_out, absmax, out);
}

// Round 18
// 93.877 us; speedup vs baseline: 1.4405x; 1.0489x over previous
//
#include <hip/hip_runtime.h>
#include <stdint.h>

#define B_   16
#define CIN  4
#define COUT 8
#define H_   512
#define W_   512
#define HP   (H_ + 2)
#define WP   (W_ + 2)
#define PMAX 756
#define TBL  (2 * PMAX + 1)
#define RPB  8                    // output rows per block
#define GY   (H_ / RPB)           // 64
#define NBLK (2 * GY * B_)        // 2048 blocks
#define NQ   (B_ * HP)            // 8224 quant blocks (div by 8)

__device__ __forceinline__ int dot4(uint32_t a, int b, int c) {
#if __has_builtin(__builtin_amdgcn_sdot4)
    return __builtin_amdgcn_sdot4((int)a, b, c, false);
#else
    int r = c;
#pragma unroll
    for (int i = 0; i < 4; ++i) {
        int av = (int)((a >> (8 * i)) & 0xFFu);
        int bv = ((int)(((uint32_t)b) << (24 - 8 * i))) >> 24;
        r += av * bv;
    }
    return r;
#endif
}

__device__ __forceinline__ int dot8(uint32_t a, int b, int c) {
#if __has_builtin(__builtin_amdgcn_sdot8)
    return __builtin_amdgcn_sdot8((int)a, b, c, false);
#else
    int r = c;
#pragma unroll
    for (int i = 0; i < 8; ++i) {
        int av = (int)((a >> (4 * i)) & 0xFu);
        int bv = ((int)(((uint32_t)b) << (28 - 4 * i))) >> 28;
        r += av * bv;
    }
    return r;
#endif
}

__device__ __forceinline__ float rfl_f(float v) {
    return __int_as_float(__builtin_amdgcn_readfirstlane(__float_as_int(v)));
}
__device__ __forceinline__ float recip1(float d) {
    float y0 = __builtin_amdgcn_rcpf(d);
    float e  = fmaf(-d, y0, 1.0f);
    return fmaf(y0, e, y0);
}
// Markstein correctly-rounded division (bit-exact vs __fdiv_rn; validated r12/r13)
__device__ __forceinline__ float mdiv(float n, float d, float y) {
    float q0 = __fmul_rn(n, y);
    float rr = fmaf(-d, q0, n);
    return fmaf(rr, y, q0);
}

__device__ __forceinline__ int wquant(const float* w, float s_w,
                                      int co, int ci, int tap) {
    const int kh = tap / 3, kw = tap % 3;
    float wv = w[((co * CIN + ci) * 3 + kh) * 3 + kw];
    float q  = rintf(__fdiv_rn(wv, s_w));
    q = fminf(fmaxf(q, -7.0f), 7.0f);
    return (int)q;
}

// ---------------- quant + weight pack ----------------
__global__ __launch_bounds__(128) void quant_pack_kernel(
        const float* __restrict__ x, const float* __restrict__ weight,
        const float* __restrict__ s_in_p, const float* __restrict__ s_w_p,
        uint32_t* __restrict__ xq, uint32_t* __restrict__ wq8) {
    const int raw = blockIdx.x;
    const int lin = (raw & 7) * (NQ / 8) + (raw >> 3);
    const int b = lin / HP, hp = lin % HP;
    const int t = threadIdx.x;
    if (raw == 0) {
        const float s_w = *s_w_p;
        if (t < 32) {                        // nibble pairs (0,1)(3,4)(6,7)(2,5)
            const int co = t >> 2, p = t & 3;
            const int tA = (p == 0) ? 0 : (p == 1) ? 3 : (p == 2) ? 6 : 2;
            const int tB = (p == 0) ? 1 : (p == 1) ? 4 : (p == 2) ? 7 : 5;
            uint32_t v = 0;
#pragma unroll
            for (int ci = 0; ci < CIN; ++ci) {
                v |= ((uint32_t)(wquant(weight, s_w, co, ci, tA) & 0xF)) << (8 * ci);
                v |= ((uint32_t)(wquant(weight, s_w, co, ci, tB) & 0xF)) << (8 * ci + 4);
            }
            wq8[t] = v;
        } else if (t < 40) {                 // tap-8 bytes
            const int co = t - 32;
            uint32_t v = 0;
#pragma unroll
            for (int ci = 0; ci < CIN; ++ci)
                v |= ((uint32_t)(wquant(weight, s_w, co, ci, 8) & 0xFF)) << (8 * ci);
            wq8[32 + co] = v;
        }
    }
    uint32_t* dst = xq + ((size_t)b * HP + hp) * WP;
    if (hp == 0 || hp == HP - 1) {
        for (int i = t; i < WP; i += 128) dst[i] = 0;
        return;
    }
    const float s_in = *s_in_p;
    const float yin  = recip1(s_in);
    const int h = hp - 1;
    const size_t plane = (size_t)H_ * W_;
    const float* xr = x + ((size_t)b * CIN) * plane + (size_t)h * W_ + 4 * t;
    float4 v0 = *(const float4*)(xr);
    float4 v1 = *(const float4*)(xr + plane);
    float4 v2 = *(const float4*)(xr + 2 * plane);
    float4 v3 = *(const float4*)(xr + 3 * plane);
    uint32_t o0 = 0, o1 = 0, o2 = 0, o3 = 0;
#define QP(f, ci, oj)                                                  \
    { float q = rintf(mdiv((f), s_in, yin));                           \
      q = fminf(fmaxf(q, 0.0f), 255.0f);                               \
      oj |= ((uint32_t)(int)q) << (8 * (ci)); }
    QP(v0.x, 0, o0) QP(v0.y, 0, o1) QP(v0.z, 0, o2) QP(v0.w, 0, o3)
    QP(v1.x, 1, o0) QP(v1.y, 1, o1) QP(v1.z, 1, o2) QP(v1.w, 1, o3)
    QP(v2.x, 2, o0) QP(v2.y, 2, o1) QP(v2.z, 2, o2) QP(v2.w, 2, o3)
    QP(v3.x, 3, o0) QP(v3.y, 3, o1) QP(v3.z, 3, o2) QP(v3.w, 3, o3)
#undef QP
    uint32_t* d = dst + 1 + 4 * t;
    uint4 vv;
    vv.x = o0; vv.y = o1; vv.z = o2; vv.w = o3;
    *(uint4*)d = vv;
    if (t == 0) dst[0] = 0;
    if (t == 127) dst[WP - 1] = 0;
}

// ---------------- shared conv machinery (r15 champion form) ----------------
#define LOADW()                                                              \
    int w8s[32], w4s[8];                                                     \
    {                                                                        \
        const int4* q4 = (const int4*)wq8;                                   \
        _Pragma("unroll")                                                    \
        for (int i = 0; i < 8; ++i) {                                        \
            int4 w4i = q4[i];                                                \
            w8s[4 * i + 0] = w4i.x;                                          \
            w8s[4 * i + 1] = w4i.y;                                          \
            w8s[4 * i + 2] = w4i.z;                                          \
            w8s[4 * i + 3] = w4i.w;                                          \
        }                                                                    \
        int4 a0 = q4[8], a1 = q4[9];                                         \
        w4s[0] = a0.x; w4s[1] = a0.y; w4s[2] = a0.z; w4s[3] = a0.w;          \
        w4s[4] = a1.x; w4s[5] = a1.y; w4s[6] = a1.z; w4s[7] = a1.w;          \
    }

#define SWZ()                                                                \
    const int raw = blockIdx.x;                                              \
    const int lin = (raw & 7) * (NBLK / 8) + (raw >> 3);                     \
    const int bx = lin & 1;                                                  \
    const int hy = (lin >> 1) & (GY - 1);                                    \
    const int b  = lin >> 7;                                                 \
    const int w0 = bx * 256 + threadIdx.x;                                   \
    const int h0 = hy * RPB;

#define EXTS(CA, SG, v0, v1, v2)                                             \
    do {                                                                     \
        uint32_t lo_ = ((v0) & 0x0F0F0F0Fu) | (((v1) << 4) & 0xF0F0F0F0u);   \
        uint32_t hi_ = (((v0) >> 4) & 0x0F0F0F0Fu) | ((v1) & 0xF0F0F0F0u);   \
        CA[0] = lo_ & 0x33333333u;                                           \
        CA[1] = (lo_ >> 2) & 0x33333333u;                                    \
        CA[2] = hi_ & 0x33333333u;                                           \
        CA[3] = (hi_ >> 2) & 0x33333333u;                                    \
        SG[0] = (v2)&0x03030303u;                                            \
        SG[1] = ((v2) >> 2) & 0x03030303u;                                   \
        SG[2] = ((v2) >> 4) & 0x03030303u;                                   \
        SG[3] = ((v2) >> 6) & 0x03030303u;                                   \
    } while (0)

#define RING_INIT()                                                          \
    uint32_t cA0[4], cA1[4], cA2[4], cA3[4];                                 \
    uint32_t sg0[4], sg1[4], sg2[4], sg3[4];                                 \
    {                                                                        \
        uint32_t r0 = base[0], r1 = base[1], r2 = base[2];                   \
        EXTS(cA0, sg0, r0, r1, r2);                                          \
        r0 = base[WP]; r1 = base[WP + 1]; r2 = base[WP + 2];                 \
        EXTS(cA1, sg1, r0, r1, r2);                                          \
    }                                                                        \
    uint32_t n0 = base[2 * WP], n1 = base[2 * WP + 1], n2 = base[2 * WP + 2];

#define PREF(S)                                                              \
    if ((S) < RPB - 1) {                                                     \
        const uint32_t* nr_ = base + (size_t)((S) + 3) * WP;                 \
        n0 = nr_[0]; n1 = nr_[1]; n2 = nr_[2];                               \
    }

#define DOTS(CAa, SGa, CAb, SGb, CAc, SGc, K, INIT, OUTV)                    \
    {                                                                        \
        int a_ = dot4(SGc[K], w4s[co], INIT);                                \
        a_ = dot8(CAa[K], w8s[co * 4 + 0], a_);                              \
        a_ = dot8(CAb[K], w8s[co * 4 + 1], a_);                              \
        a_ = dot8(CAc[K], w8s[co * 4 + 2], a_);                              \
        a_ = dot8(K == 0 ? pc0 : K == 1 ? pc1 : K == 2 ? pc2 : pc3,          \
                  w8s[co * 4 + 3], a_);                                      \
        OUTV = a_;                                                           \
    }

// ---------------- pass 1: absmax (pair-fold -> v_max3/v_min3) ----------------
#define STEP1(S, CAa, SGa, CAb, SGb, CAc, SGc)                               \
    do {                                                                     \
        EXTS(CAc, SGc, n0, n1, n2);                                          \
        PREF(S);                                                             \
        const uint32_t pc0 = SGa[0] | (SGb[0] << 4);                         \
        const uint32_t pc1 = SGa[1] | (SGb[1] << 4);                         \
        const uint32_t pc2 = SGa[2] | (SGb[2] << 4);                         \
        const uint32_t pc3 = SGa[3] | (SGb[3] << 4);                         \
        _Pragma("unroll")                                                    \
        for (int cp = 0; cp < COUT / 2; ++cp) {                              \
            int p0, p1, p2, p3, q0, q1, q2, q3;                              \
            {                                                                \
                const int co = 2 * cp;                                       \
                DOTS(CAa, SGa, CAb, SGb, CAc, SGc, 0, 0, p0);                \
                DOTS(CAa, SGa, CAb, SGb, CAc, SGc, 1, 0, p1);                \
                DOTS(CAa, SGa, CAb, SGb, CAc, SGc, 2, 0, p2);                \
                DOTS(CAa, SGa, CAb, SGb, CAc, SGc, 3, 0, p3);                \
            }                                                                \
            {                                                                \
                const int co = 2 * cp + 1;                                   \
                DOTS(CAa, SGa, CAb, SGb, CAc, SGc, 0, 0, q0);                \
                DOTS(CAa, SGa, CAb, SGb, CAc, SGc, 1, 0, q1);                \
                DOTS(CAa, SGa, CAb, SGb, CAc, SGc, 2, 0, q2);                \
                DOTS(CAa, SGa, CAb, SGb, CAc, SGc, 3, 0, q3);                \
            }                                                                \
            /* max(max(p,q), acc) -> single v_max3_i32; same for min3 */     \
            rMax0 = max(rMax0, max(p0, q0)); rMin0 = min(rMin0, min(p0, q0));\
            rMax1 = max(rMax1, max(p1, q1)); rMin1 = min(rMin1, min(p1, q1));\
            rMax2 = max(rMax2, max(p2, q2)); rMin2 = min(rMin2, min(p2, q2));\
            rMax3 = max(rMax3, max(p3, q3)); rMin3 = min(rMin3, min(p3, q3));\
        }                                                                    \
    } while (0)

__global__ __launch_bounds__(256, 2) void conv_absmax(
        const uint32_t* __restrict__ xq, const uint32_t* __restrict__ wq8,
        int* __restrict__ blkmax) {
    __shared__ int red[4];
    LOADW();
    SWZ();
    const uint32_t* base = xq + ((size_t)b * HP + h0) * WP + w0;
    RING_INIT();
    int rMax0 = 0, rMax1 = 0, rMax2 = 0, rMax3 = 0;
    int rMin0 = 0, rMin1 = 0, rMin2 = 0, rMin3 = 0;
    STEP1(0, cA0, sg0, cA1, sg1, cA2, sg2);
    STEP1(1, cA1, sg1, cA2, sg2, cA3, sg3);
    STEP1(2, cA2, sg2, cA3, sg3, cA0, sg0);
    STEP1(3, cA3, sg3, cA0, sg0, cA1, sg1);
    STEP1(4, cA0, sg0, cA1, sg1, cA2, sg2);
    STEP1(5, cA1, sg1, cA2, sg2, cA3, sg3);
    STEP1(6, cA2, sg2, cA3, sg3, cA0, sg0);
    STEP1(7, cA3, sg3, cA0, sg0, cA1, sg1);
    int m = max(max(max(rMax0, -rMin0), max(rMax1, -rMin1)),
                max(max(rMax2, -rMin2), max(rMax3, -rMin3)));
#pragma unroll
    for (int off = 1; off < 64; off <<= 1)
        m = max(m, __shfl_xor(m, off));
    if ((threadIdx.x & 63) == 0) red[threadIdx.x >> 6] = m;
    __syncthreads();
    if (threadIdx.x == 0)
        blkmax[raw] = max(max(red[0], red[1]), max(red[2], red[3]));
}

__global__ __launch_bounds__(256) void reduce_absmax(
        const int* __restrict__ blkmax, int* __restrict__ absmax) {
    __shared__ int red[4];
    const int t = threadIdx.x;
    int m = 0;
#pragma unroll
    for (int i = 0; i < NBLK / 256; ++i) m = max(m, blkmax[t + 256 * i]);
#pragma unroll
    for (int off = 1; off < 64; off <<= 1)
        m = max(m, __shfl_xor(m, off));
    if ((t & 63) == 0) red[t >> 6] = m;
    __syncthreads();
    if (t == 0)
        *absmax = max(max(red[0], red[1]), max(red[2], red[3]));
}

// ---------------- pass 2: LUT + dieted epilogue (r15 champion, unchanged) ----
#define STEP2(S, CAa, SGa, CAb, SGb, CAc, SGc)                               \
    do {                                                                     \
        EXTS(CAc, SGc, n0, n1, n2);                                          \
        PREF(S);                                                             \
        const uint32_t pc0 = SGa[0] | (SGb[0] << 4);                         \
        const uint32_t pc1 = SGa[1] | (SGb[1] << 4);                         \
        const uint32_t pc2 = SGa[2] | (SGb[2] << 4);                         \
        const uint32_t pc3 = SGa[3] | (SGb[3] << 4);                         \
        int ax[COUT][4];                                                     \
        _Pragma("unroll")                                                    \
        for (int co = 0; co < COUT; ++co) {                                  \
            DOTS(CAa, SGa, CAb, SGb, CAc, SGc, 0, PMAX, ax[co][0]);          \
            DOTS(CAa, SGa, CAb, SGb, CAc, SGc, 1, PMAX, ax[co][1]);          \
            DOTS(CAa, SGa, CAb, SGb, CAc, SGc, 2, PMAX, ax[co][2]);          \
            DOTS(CAa, SGa, CAb, SGb, CAc, SGc, 3, PMAX, ax[co][3]);          \
        }                                                                    \
        float tv[COUT][4];                                                   \
        _Pragma("unroll")                                                    \
        for (int co = 0; co < COUT; ++co) {                                  \
            tv[co][0] = T0[ax[co][0]];                                       \
            tv[co][1] = T4[ax[co][1]];                                       \
            tv[co][2] = T0[ax[co][2]];                                       \
            tv[co][3] = T4[ax[co][3]];                                       \
        }                                                                    \
        float* orow = out + ((size_t)b * COUT * H_ + (size_t)(h0 + (S))) * W_ + w0; \
        _Pragma("unroll")                                                    \
        for (int co = 0; co < COUT; ++co) {                                  \
            float of = __fadd_rn(tv[co][0], tv[co][1]);                      \
            of = __fadd_rn(of, __fmul_rn(tv[co][2], 16.0f));                 \
            of = __fadd_rn(of, __fmul_rn(tv[co][3], 16.0f));                 \
            float o_ = __fadd_rn(__fmul_rn(of, scale), br[co]);              \
            float q0 = __fmul_rn(o_, y1);                                    \
            float rr = fmaf(-s_out, q0, o_);                                 \
            float qd = fmaf(rr, y1, q0);                                     \
            float q_ = rintf(qd);                                            \
            q_ = fminf(fmaxf(q_, -127.0f), 127.0f);                          \
            orow[(size_t)co * plane] = __fmul_rn(q_, s_out);                 \
        }                                                                    \
    } while (0)

__global__ __launch_bounds__(256, 2) void conv_out(
        const uint32_t* __restrict__ xq, const uint32_t* __restrict__ wq8,
        const float* __restrict__ bias, const float* __restrict__ sp_in,
        const float* __restrict__ sp_w, const float* __restrict__ sp_out,
        const int* __restrict__ absmax, float* __restrict__ out) {
    __shared__ float T0[TBL];
    __shared__ float T4[TBL];
    LOADW();
    const float pabs = fmaxf((float)(*absmax), 1e-6f);
    const float c63  = 1.0f / 63.0f;
    float g = rintf(__fdiv_rn(127.0f, __fmul_rn(pabs, c63)));
    g = fminf(fmaxf(g, 1.0f), 255.0f);
    const float step = __fdiv_rn(1.0f, __fmul_rn(g, c63));
    for (int i = threadIdx.x; i < TBL; i += 256) {
        float p = (float)(i - PMAX);
        float r = rintf(__fdiv_rn(p, step));
        r = fminf(fmaxf(r, -127.0f), 127.0f);
        float v = __fmul_rn(r, step);
        T0[i] = v;
        T4[i] = 4.0f * v;          // exact
    }
    const float scale = __fmul_rn(rfl_f(*sp_in), rfl_f(*sp_w));
    const float s_out = rfl_f(*sp_out);
    const float y1    = recip1(s_out);
    float br[COUT];
#pragma unroll
    for (int co = 0; co < COUT; ++co) br[co] = rfl_f(bias[co]);
    __syncthreads();

    SWZ();
    const uint32_t* base = xq + ((size_t)b * HP + h0) * WP + w0;
    const size_t plane = (size_t)H_ * W_;
    RING_INIT();
    STEP2(0, cA0, sg0, cA1, sg1, cA2, sg2);
    STEP2(1, cA1, sg1, cA2, sg2, cA3, sg3);
    STEP2(2, cA2, sg2, cA3, sg3, cA0, sg0);
    STEP2(3, cA3, sg3, cA0, sg0, cA1, sg1);
    STEP2(4, cA0, sg0, cA1, sg1, cA2, sg2);
    STEP2(5, cA1, sg1, cA2, sg2, cA3, sg3);
    STEP2(6, cA2, sg2, cA3, sg3, cA0, sg0);
    STEP2(7, cA3, sg3, cA0, sg0, cA1, sg1);
}

extern "C" void kernel_launch(void* const* d_in, const int* in_sizes, int n_in,
                              void* d_out, int out_size, void* d_ws, size_t ws_size,
                              hipStream_t stream) {
    const float* x      = (const float*)d_in[0];
    const float* weight = (const float*)d_in[1];
    const float* bias   = (const float*)d_in[2];
    const float* s_in   = (const float*)d_in[3];
    const float* s_w    = (const float*)d_in[4];
    const float* s_out  = (const float*)d_in[5];
    float* out = (float*)d_out;

    int*      absmax = (int*)d_ws;
    uint32_t* wq8    = (uint32_t*)((char*)d_ws + 256);    // 40 u32
    int*      blkmax = (int*)((char*)d_ws + 1024);        // 2048 ints
    uint32_t* xq     = (uint32_t*)((char*)d_ws + 16384);

    quant_pack_kernel<<<dim3(NQ), dim3(128), 0, stream>>>(
        x, weight, s_in, s_w, xq, wq8);

    conv_absmax<<<dim3(NBLK), dim3(256), 0, stream>>>(xq, wq8, blkmax);

    reduce_absmax<<<dim3(1), dim3(256), 0, stream>>>(blkmax, absmax);

    conv_out<<<dim3(NBLK), dim3(256), 0, stream>>>(
        xq, wq8, bias, s_in, s_w, s_out, absmax, out);
}

// Round 19
// 92.612 us; speedup vs baseline: 1.4602x; 1.0137x over previous
//
#include <hip/hip_runtime.h>
#include <stdint.h>

#define B_   16
#define CIN  4
#define COUT 8
#define H_   512
#define W_   512
#define HP   (H_ + 2)
#define WP   (W_ + 2)
#define PMAX 756
#define TBL  (2 * PMAX + 1)
#define RPB  8                    // output rows per block
#define GY   (H_ / RPB)           // 64
#define NBLK (2 * GY * B_)        // 2048 blocks
#define NQ   (B_ * HP)            // 8224 quant blocks (div by 8)

__device__ __forceinline__ int dot4(uint32_t a, int b, int c) {
#if __has_builtin(__builtin_amdgcn_sdot4)
    return __builtin_amdgcn_sdot4((int)a, b, c, false);
#else
    int r = c;
#pragma unroll
    for (int i = 0; i < 4; ++i) {
        int av = (int)((a >> (8 * i)) & 0xFFu);
        int bv = ((int)(((uint32_t)b) << (24 - 8 * i))) >> 24;
        r += av * bv;
    }
    return r;
#endif
}

__device__ __forceinline__ int dot8(uint32_t a, int b, int c) {
#if __has_builtin(__builtin_amdgcn_sdot8)
    return __builtin_amdgcn_sdot8((int)a, b, c, false);
#else
    int r = c;
#pragma unroll
    for (int i = 0; i < 8; ++i) {
        int av = (int)((a >> (4 * i)) & 0xFu);
        int bv = ((int)(((uint32_t)b) << (28 - 4 * i))) >> 28;
        r += av * bv;
    }
    return r;
#endif
}

__device__ __forceinline__ float rfl_f(float v) {
    return __int_as_float(__builtin_amdgcn_readfirstlane(__float_as_int(v)));
}
__device__ __forceinline__ float recip1(float d) {
    float y0 = __builtin_amdgcn_rcpf(d);
    float e  = fmaf(-d, y0, 1.0f);
    return fmaf(y0, e, y0);
}
// Markstein correctly-rounded division (bit-exact vs __fdiv_rn; validated r12/r13)
__device__ __forceinline__ float mdiv(float n, float d, float y) {
    float q0 = __fmul_rn(n, y);
    float rr = fmaf(-d, q0, n);
    return fmaf(rr, y, q0);
}

__device__ __forceinline__ int wquant(const float* w, float s_w,
                                      int co, int ci, int tap) {
    const int kh = tap / 3, kw = tap % 3;
    float wv = w[((co * CIN + ci) * 3 + kh) * 3 + kw];
    float q  = rintf(__fdiv_rn(wv, s_w));
    q = fminf(fmaxf(q, -7.0f), 7.0f);
    return (int)q;
}

// ---------------- quant + weight pack ----------------
__global__ __launch_bounds__(128) void quant_pack_kernel(
        const float* __restrict__ x, const float* __restrict__ weight,
        const float* __restrict__ s_in_p, const float* __restrict__ s_w_p,
        uint32_t* __restrict__ xq, uint32_t* __restrict__ wq8) {
    const int raw = blockIdx.x;
    const int lin = (raw & 7) * (NQ / 8) + (raw >> 3);
    const int b = lin / HP, hp = lin % HP;
    const int t = threadIdx.x;
    if (raw == 0) {
        const float s_w = *s_w_p;
        if (t < 32) {                        // nibble pairs (0,1)(3,4)(6,7)(2,5)
            const int co = t >> 2, p = t & 3;
            const int tA = (p == 0) ? 0 : (p == 1) ? 3 : (p == 2) ? 6 : 2;
            const int tB = (p == 0) ? 1 : (p == 1) ? 4 : (p == 2) ? 7 : 5;
            uint32_t v = 0;
#pragma unroll
            for (int ci = 0; ci < CIN; ++ci) {
                v |= ((uint32_t)(wquant(weight, s_w, co, ci, tA) & 0xF)) << (8 * ci);
                v |= ((uint32_t)(wquant(weight, s_w, co, ci, tB) & 0xF)) << (8 * ci + 4);
            }
            wq8[t] = v;
        } else if (t < 40) {                 // tap-8 bytes
            const int co = t - 32;
            uint32_t v = 0;
#pragma unroll
            for (int ci = 0; ci < CIN; ++ci)
                v |= ((uint32_t)(wquant(weight, s_w, co, ci, 8) & 0xFF)) << (8 * ci);
            wq8[32 + co] = v;
        }
    }
    uint32_t* dst = xq + ((size_t)b * HP + hp) * WP;
    if (hp == 0 || hp == HP - 1) {
        for (int i = t; i < WP; i += 128) dst[i] = 0;
        return;
    }
    const float s_in = *s_in_p;
    const float yin  = recip1(s_in);
    const int h = hp - 1;
    const size_t plane = (size_t)H_ * W_;
    const float* xr = x + ((size_t)b * CIN) * plane + (size_t)h * W_ + 4 * t;
    float4 v0 = *(const float4*)(xr);
    float4 v1 = *(const float4*)(xr + plane);
    float4 v2 = *(const float4*)(xr + 2 * plane);
    float4 v3 = *(const float4*)(xr + 3 * plane);
    uint32_t o0 = 0, o1 = 0, o2 = 0, o3 = 0;
#define QP(f, ci, oj)                                                  \
    { float q = rintf(mdiv((f), s_in, yin));                           \
      q = fminf(fmaxf(q, 0.0f), 255.0f);                               \
      oj |= ((uint32_t)(int)q) << (8 * (ci)); }
    QP(v0.x, 0, o0) QP(v0.y, 0, o1) QP(v0.z, 0, o2) QP(v0.w, 0, o3)
    QP(v1.x, 1, o0) QP(v1.y, 1, o1) QP(v1.z, 1, o2) QP(v1.w, 1, o3)
    QP(v2.x, 2, o0) QP(v2.y, 2, o1) QP(v2.z, 2, o2) QP(v2.w, 2, o3)
    QP(v3.x, 3, o0) QP(v3.y, 3, o1) QP(v3.z, 3, o2) QP(v3.w, 3, o3)
#undef QP
    uint32_t* d = dst + 1 + 4 * t;
    uint4 vv;
    vv.x = o0; vv.y = o1; vv.z = o2; vv.w = o3;
    *(uint4*)d = vv;
    if (t == 0) dst[0] = 0;
    if (t == 127) dst[WP - 1] = 0;
}

// ---------------- shared conv machinery (r15 champion form) ----------------
#define LOADW()                                                              \
    int w8s[32], w4s[8];                                                     \
    {                                                                        \
        const int4* q4 = (const int4*)wq8;                                   \
        _Pragma("unroll")                                                    \
        for (int i = 0; i < 8; ++i) {                                        \
            int4 w4i = q4[i];                                                \
            w8s[4 * i + 0] = w4i.x;                                          \
            w8s[4 * i + 1] = w4i.y;                                          \
            w8s[4 * i + 2] = w4i.z;                                          \
            w8s[4 * i + 3] = w4i.w;                                          \
        }                                                                    \
        int4 a0 = q4[8], a1 = q4[9];                                         \
        w4s[0] = a0.x; w4s[1] = a0.y; w4s[2] = a0.z; w4s[3] = a0.w;          \
        w4s[4] = a1.x; w4s[5] = a1.y; w4s[6] = a1.z; w4s[7] = a1.w;          \
    }

#define SWZ()                                                                \
    const int raw = blockIdx.x;                                              \
    const int lin = (raw & 7) * (NBLK / 8) + (raw >> 3);                     \
    const int bx = lin & 1;                                                  \
    const int hy = (lin >> 1) & (GY - 1);                                    \
    const int b  = lin >> 7;                                                 \
    const int w0 = bx * 256 + threadIdx.x;                                   \
    const int h0 = hy * RPB;

#define EXTS(CA, SG, v0, v1, v2)                                             \
    do {                                                                     \
        uint32_t lo_ = ((v0) & 0x0F0F0F0Fu) | (((v1) << 4) & 0xF0F0F0F0u);   \
        uint32_t hi_ = (((v0) >> 4) & 0x0F0F0F0Fu) | ((v1) & 0xF0F0F0F0u);   \
        CA[0] = lo_ & 0x33333333u;                                           \
        CA[1] = (lo_ >> 2) & 0x33333333u;                                    \
        CA[2] = hi_ & 0x33333333u;                                           \
        CA[3] = (hi_ >> 2) & 0x33333333u;                                    \
        SG[0] = (v2)&0x03030303u;                                            \
        SG[1] = ((v2) >> 2) & 0x03030303u;                                   \
        SG[2] = ((v2) >> 4) & 0x03030303u;                                   \
        SG[3] = ((v2) >> 6) & 0x03030303u;                                   \
    } while (0)

#define RING_INIT()                                                          \
    uint32_t cA0[4], cA1[4], cA2[4], cA3[4];                                 \
    uint32_t sg0[4], sg1[4], sg2[4], sg3[4];                                 \
    {                                                                        \
        uint32_t r0 = base[0], r1 = base[1], r2 = base[2];                   \
        EXTS(cA0, sg0, r0, r1, r2);                                          \
        r0 = base[WP]; r1 = base[WP + 1]; r2 = base[WP + 2];                 \
        EXTS(cA1, sg1, r0, r1, r2);                                          \
    }                                                                        \
    uint32_t n0 = base[2 * WP], n1 = base[2 * WP + 1], n2 = base[2 * WP + 2];

#define PREF(S)                                                              \
    if ((S) < RPB - 1) {                                                     \
        const uint32_t* nr_ = base + (size_t)((S) + 3) * WP;                 \
        n0 = nr_[0]; n1 = nr_[1]; n2 = nr_[2];                               \
    }

#define DOTS(CAa, SGa, CAb, SGb, CAc, SGc, K, INIT, OUTV)                    \
    {                                                                        \
        int a_ = dot4(SGc[K], w4s[co], INIT);                                \
        a_ = dot8(CAa[K], w8s[co * 4 + 0], a_);                              \
        a_ = dot8(CAb[K], w8s[co * 4 + 1], a_);                              \
        a_ = dot8(CAc[K], w8s[co * 4 + 2], a_);                              \
        a_ = dot8(K == 0 ? pc0 : K == 1 ? pc1 : K == 2 ? pc2 : pc3,          \
                  w8s[co * 4 + 3], a_);                                      \
        OUTV = a_;                                                           \
    }

// ---------------- pass 1: absmax ----------------
#define STEP1(S, CAa, SGa, CAb, SGb, CAc, SGc)                               \
    do {                                                                     \
        EXTS(CAc, SGc, n0, n1, n2);                                          \
        PREF(S);                                                             \
        const uint32_t pc0 = SGa[0] | (SGb[0] << 4);                         \
        const uint32_t pc1 = SGa[1] | (SGb[1] << 4);                         \
        const uint32_t pc2 = SGa[2] | (SGb[2] << 4);                         \
        const uint32_t pc3 = SGa[3] | (SGb[3] << 4);                         \
        _Pragma("unroll")                                                    \
        for (int co = 0; co < COUT; ++co) {                                  \
            int a0, a1, a2, a3;                                              \
            DOTS(CAa, SGa, CAb, SGb, CAc, SGc, 0, 0, a0);                    \
            DOTS(CAa, SGa, CAb, SGb, CAc, SGc, 1, 0, a1);                    \
            DOTS(CAa, SGa, CAb, SGb, CAc, SGc, 2, 0, a2);                    \
            DOTS(CAa, SGa, CAb, SGb, CAc, SGc, 3, 0, a3);                    \
            rMax0 = max(rMax0, a0); rMin0 = min(rMin0, a0);                  \
            rMax1 = max(rMax1, a1); rMin1 = min(rMin1, a1);                  \
            rMax2 = max(rMax2, a2); rMin2 = min(rMin2, a2);                  \
            rMax3 = max(rMax3, a3); rMin3 = min(rMin3, a3);                  \
        }                                                                    \
    } while (0)

__global__ __launch_bounds__(256, 2) void conv_absmax(
        const uint32_t* __restrict__ xq, const uint32_t* __restrict__ wq8,
        int* __restrict__ blkmax) {
    __shared__ int red[4];
    LOADW();
    SWZ();
    const uint32_t* base = xq + ((size_t)b * HP + h0) * WP + w0;
    RING_INIT();
    int rMax0 = 0, rMax1 = 0, rMax2 = 0, rMax3 = 0;
    int rMin0 = 0, rMin1 = 0, rMin2 = 0, rMin3 = 0;
    STEP1(0, cA0, sg0, cA1, sg1, cA2, sg2);
    STEP1(1, cA1, sg1, cA2, sg2, cA3, sg3);
    STEP1(2, cA2, sg2, cA3, sg3, cA0, sg0);
    STEP1(3, cA3, sg3, cA0, sg0, cA1, sg1);
    STEP1(4, cA0, sg0, cA1, sg1, cA2, sg2);
    STEP1(5, cA1, sg1, cA2, sg2, cA3, sg3);
    STEP1(6, cA2, sg2, cA3, sg3, cA0, sg0);
    STEP1(7, cA3, sg3, cA0, sg0, cA1, sg1);
    int m = max(max(max(rMax0, -rMin0), max(rMax1, -rMin1)),
                max(max(rMax2, -rMin2), max(rMax3, -rMin3)));
#pragma unroll
    for (int off = 1; off < 64; off <<= 1)
        m = max(m, __shfl_xor(m, off));
    if ((threadIdx.x & 63) == 0) red[threadIdx.x >> 6] = m;
    __syncthreads();
    if (threadIdx.x == 0)
        blkmax[raw] = max(max(red[0], red[1]), max(red[2], red[3]));
}

__global__ __launch_bounds__(256) void reduce_absmax(
        const int* __restrict__ blkmax, int* __restrict__ absmax) {
    __shared__ int red[4];
    const int t = threadIdx.x;
    int m = 0;
#pragma unroll
    for (int i = 0; i < NBLK / 256; ++i) m = max(m, blkmax[t + 256 * i]);
#pragma unroll
    for (int off = 1; off < 64; off <<= 1)
        m = max(m, __shfl_xor(m, off));
    if ((t & 63) == 0) red[t >> 6] = m;
    __syncthreads();
    if (t == 0)
        *absmax = max(max(red[0], red[1]), max(red[2], red[3]));
}

// ---------------- pass 2: LUT + dieted epilogue ----------------
#define STEP2(S, CAa, SGa, CAb, SGb, CAc, SGc)                               \
    do {                                                                     \
        EXTS(CAc, SGc, n0, n1, n2);                                          \
        PREF(S);                                                             \
        const uint32_t pc0 = SGa[0] | (SGb[0] << 4);                         \
        const uint32_t pc1 = SGa[1] | (SGb[1] << 4);                         \
        const uint32_t pc2 = SGa[2] | (SGb[2] << 4);                         \
        const uint32_t pc3 = SGa[3] | (SGb[3] << 4);                         \
        int ax[COUT][4];                                                     \
        _Pragma("unroll")                                                    \
        for (int co = 0; co < COUT; ++co) {                                  \
            DOTS(CAa, SGa, CAb, SGb, CAc, SGc, 0, PMAX, ax[co][0]);          \
            DOTS(CAa, SGa, CAb, SGb, CAc, SGc, 1, PMAX, ax[co][1]);          \
            DOTS(CAa, SGa, CAb, SGb, CAc, SGc, 2, PMAX, ax[co][2]);          \
            DOTS(CAa, SGa, CAb, SGb, CAc, SGc, 3, PMAX, ax[co][3]);          \
        }                                                                    \
        float tv[COUT][4];                                                   \
        _Pragma("unroll")                                                    \
        for (int co = 0; co < COUT; ++co) {                                  \
            tv[co][0] = T0[ax[co][0]];                                       \
            tv[co][1] = T4[ax[co][1]];                                       \
            tv[co][2] = T0[ax[co][2]];                                       \
            tv[co][3] = T4[ax[co][3]];                                       \
        }                                                                    \
        float* orow = out + ((size_t)b * COUT * H_ + (size_t)(h0 + (S))) * W_ + w0; \
        _Pragma("unroll")                                                    \
        for (int co = 0; co < COUT; ++co) {                                  \
            float of = __fadd_rn(tv[co][0], tv[co][1]);                      \
            of = __fadd_rn(of, __fmul_rn(tv[co][2], 16.0f));                 \
            of = __fadd_rn(of, __fmul_rn(tv[co][3], 16.0f));                 \
            float o_ = __fadd_rn(__fmul_rn(of, scale), br[co]);              \
            float q0 = __fmul_rn(o_, y1);                                    \
            float rr = fmaf(-s_out, q0, o_);                                 \
            float qd = fmaf(rr, y1, q0);                                     \
            float q_ = rintf(qd);                                            \
            q_ = fminf(fmaxf(q_, -127.0f), 127.0f);                          \
            orow[(size_t)co * plane] = __fmul_rn(q_, s_out);                 \
        }                                                                    \
    } while (0)

__global__ __launch_bounds__(256, 2) void conv_out(
        const uint32_t* __restrict__ xq, const uint32_t* __restrict__ wq8,
        const float* __restrict__ bias, const float* __restrict__ sp_in,
        const float* __restrict__ sp_w, const float* __restrict__ sp_out,
        const int* __restrict__ absmax, float* __restrict__ out) {
    __shared__ float T0[TBL];
    __shared__ float T4[TBL];
    LOADW();
    const float pabs = fmaxf((float)(*absmax), 1e-6f);
    const float c63  = 1.0f / 63.0f;
    float g = rintf(__fdiv_rn(127.0f, __fmul_rn(pabs, c63)));
    g = fminf(fmaxf(g, 1.0f), 255.0f);
    const float step = __fdiv_rn(1.0f, __fmul_rn(g, c63));
    for (int i = threadIdx.x; i < TBL; i += 256) {
        float p = (float)(i - PMAX);
        float r = rintf(__fdiv_rn(p, step));
        r = fminf(fmaxf(r, -127.0f), 127.0f);
        float v = __fmul_rn(r, step);
        T0[i] = v;
        T4[i] = 4.0f * v;          // exact
    }
    const float scale = __fmul_rn(rfl_f(*sp_in), rfl_f(*sp_w));
    const float s_out = rfl_f(*sp_out);
    const float y1    = recip1(s_out);
    float br[COUT];
#pragma unroll
    for (int co = 0; co < COUT; ++co) br[co] = rfl_f(bias[co]);
    __syncthreads();

    SWZ();
    const uint32_t* base = xq + ((size_t)b * HP + h0) * WP + w0;
    const size_t plane = (size_t)H_ * W_;
    RING_INIT();
    STEP2(0, cA0, sg0, cA1, sg1, cA2, sg2);
    STEP2(1, cA1, sg1, cA2, sg2, cA3, sg3);
    STEP2(2, cA2, sg2, cA3, sg3, cA0, sg0);
    STEP2(3, cA3, sg3, cA0, sg0, cA1, sg1);
    STEP2(4, cA0, sg0, cA1, sg1, cA2, sg2);
    STEP2(5, cA1, sg1, cA2, sg2, cA3, sg3);
    STEP2(6, cA2, sg2, cA3, sg3, cA0, sg0);
    STEP2(7, cA3, sg3, cA0, sg0, cA1, sg1);
}

extern "C" void kernel_launch(void* const* d_in, const int* in_sizes, int n_in,
                              void* d_out, int out_size, void* d_ws, size_t ws_size,
                              hipStream_t stream) {
    const float* x      = (const float*)d_in[0];
    const float* weight = (const float*)d_in[1];
    const float* bias   = (const float*)d_in[2];
    const float* s_in   = (const float*)d_in[3];
    const float* s_w    = (const float*)d_in[4];
    const float* s_out  = (const float*)d_in[5];
    float* out = (float*)d_out;

    int*      absmax = (int*)d_ws;
    uint32_t* wq8    = (uint32_t*)((char*)d_ws + 256);    // 40 u32
    int*      blkmax = (int*)((char*)d_ws + 1024);        // 2048 ints
    uint32_t* xq     = (uint32_t*)((char*)d_ws + 16384);

    quant_pack_kernel<<<dim3(NQ), dim3(128), 0, stream>>>(
        x, weight, s_in, s_w, xq, wq8);

    conv_absmax<<<dim3(NBLK), dim3(256), 0, stream>>>(xq, wq8, blkmax);

    reduce_absmax<<<dim3(1), dim3(256), 0, stream>>>(blkmax, absmax);

    conv_out<<<dim3(NBLK), dim3(256), 0, stream>>>(
        xq, wq8, bias, s_in, s_w, s_out, absmax, out);
}